// Round 13
// baseline (274.229 us; speedup 1.0000x reference)
//
#include <hip/hip_runtime.h>
#include <hip/hip_cooperative_groups.h>
#include <math.h>

namespace cg = cooperative_groups;

// Problem constants (C = RC = 1)
#define BB 2
#define SS 1024
#define DD 1024
#define NH 16
#define DH 64
#define MAXN 0.996f   // (1 - PROJ_EPS)/RC

typedef __attribute__((ext_vector_type(8))) short bf16x8;  // MFMA A/B frag (4 VGPRs)
typedef __attribute__((ext_vector_type(4))) float f32x4;   // MFMA C/D frag

__device__ __forceinline__ float xor_sum16(float v){
  v += __shfl_xor(v, 1, 64);
  v += __shfl_xor(v, 2, 64);
  v += __shfl_xor(v, 4, 64);
  v += __shfl_xor(v, 8, 64);
  return v;
}

__device__ __forceinline__ unsigned short f2bf(float x){
  unsigned u = __builtin_bit_cast(unsigned, x);
  unsigned r = u + 0x7FFFu + ((u >> 16) & 1u);   // RNE
  return (unsigned short)(r >> 16);
}
__device__ __forceinline__ float bf2f(unsigned short b){
  unsigned u = ((unsigned)b) << 16;
  return __builtin_bit_cast(float, u);
}

// async global->LDS DMA: per-lane 16B from g, landing at wave-uniform s + lane*16
__device__ __forceinline__ void async_copy16(const unsigned short* g, unsigned short* s){
  __builtin_amdgcn_global_load_lds(
      (const __attribute__((address_space(1))) unsigned int*)g,
      (__attribute__((address_space(3))) unsigned int*)s,
      16, 0, 0);
}

// ---------------- K1: fused prep (one launch) ----------------
// v13: col_stats folded into convert_zt (partial col-sums); stats finalization
// now lives in the gemm epilogue (v15) - no finalize kernel.
// blocks [0,1024): convert_x (split-bf16) + fused per-row ||x||^2 (2 rows/block)
// blocks [1024,1792): convert_zt (z -> split-bf16 transposed ZT[mat][n][k]) + col-partials
__global__ __launch_bounds__(256) void prep_kernel(
    const float* __restrict__ hs,
    const float* __restrict__ zq, const float* __restrict__ zk, const float* __restrict__ zv,
    float* __restrict__ cx2, float* __restrict__ partial,
    unsigned short* __restrict__ Xhi, unsigned short* __restrict__ Xlo,
    unsigned short* __restrict__ ZThi, unsigned short* __restrict__ ZTlo)
{
  __shared__ unsigned shbuf[64 * 69];     // 17.6 KB, aliased per role
  __shared__ float csred[4][64];          // cross-wave col-sum reduce (convert_zt)
  const int bid = blockIdx.x;
  const int tid = threadIdx.x;

  if (bid < 1024) {
    // ---- convert_x + row ||x||^2 (rows 2b, 2b+1) ----
    const int b = bid;
    const size_t g0 = (size_t)b * 2048 + (size_t)tid * 8;
    float acc = 0.0f;
    #pragma unroll
    for (int h = 0; h < 2; ++h) {
      float4 v = *(const float4*)(hs + g0 + 4 * h);
      float a[4] = {v.x, v.y, v.z, v.w};
      ushort4 hv, lv;
      unsigned short* hp = (unsigned short*)&hv;
      unsigned short* lp = (unsigned short*)&lv;
      #pragma unroll
      for (int j = 0; j < 4; ++j) {
        acc = fmaf(a[j], a[j], acc);
        unsigned short hi = f2bf(a[j]);
        hp[j] = hi;
        lp[j] = f2bf(a[j] - bf2f(hi));
      }
      *(ushort4*)(Xhi + g0 + 4 * h) = hv;
      *(ushort4*)(Xlo + g0 + 4 * h) = lv;
    }
    #pragma unroll
    for (int m = 1; m < 64; m <<= 1) acc += __shfl_xor(acc, m, 64);
    float* red = (float*)shbuf;
    const int wave = tid >> 6, lane = tid & 63;
    if (lane == 0) red[wave] = acc;
    __syncthreads();
    if (tid == 0)   cx2[2 * b]     = red[0] + red[1];
    if (tid == 128) cx2[2 * b + 1] = red[2] + red[3];
  } else {
    // ---- convert_zt + column-sum partials ----
    const int b2 = bid - 1024;
    const int kt = b2 & 15, nt = (b2 >> 4) & 15, mat = b2 >> 8;
    const float* z = (mat == 0) ? zq : ((mat == 1) ? zk : zv);
    const int wave = tid >> 6, lane = tid & 63;
    unsigned (*T)[69] = (unsigned(*)[69])shbuf;
    float cs[4] = {0.f, 0.f, 0.f, 0.f};
    #pragma unroll
    for (int i = 0; i < 4; ++i) {
      const int g = tid + 256 * i;
      const int kr = g >> 4, nc = (g & 15) * 4;   // nc fixed per thread
      float4 v = *(const float4*)(z + (size_t)(kt * 64 + kr) * DD + nt * 64 + nc);
      float a[4] = {v.x, v.y, v.z, v.w};
      #pragma unroll
      for (int j = 0; j < 4; ++j) {
        cs[j] = fmaf(a[j], a[j], cs[j]);
        unsigned short hi = f2bf(a[j]);
        unsigned short lo = f2bf(a[j] - bf2f(hi));
        T[kr][nc + j] = ((unsigned)lo << 16) | (unsigned)hi;
      }
    }
    // intra-wave reduce over row-groups (lanes l, l^16, l^32, l^48 share cols)
    #pragma unroll
    for (int j = 0; j < 4; ++j) {
      cs[j] += __shfl_xor(cs[j], 16, 64);
      cs[j] += __shfl_xor(cs[j], 32, 64);
    }
    if (lane < 16) {
      #pragma unroll
      for (int j = 0; j < 4; ++j) csred[wave][lane * 4 + j] = cs[j];
    }
    __syncthreads();
    #pragma unroll
    for (int i = 0; i < 4; ++i) {
      const int g = tid + 256 * i;
      const int nr = g >> 4, kc = (g & 15) * 4;
      ushort4 hv, lv;
      unsigned short* hp = (unsigned short*)&hv;
      unsigned short* lp = (unsigned short*)&lv;
      #pragma unroll
      for (int j = 0; j < 4; ++j) {
        unsigned u = T[kc + j][nr];
        hp[j] = (unsigned short)(u & 0xFFFFu);
        lp[j] = (unsigned short)(u >> 16);
      }
      const size_t ob = ((size_t)mat * DD + nt * 64 + nr) * DD + kt * 64 + kc;
      *(ushort4*)(ZThi + ob) = hv;
      *(ushort4*)(ZTlo + ob) = lv;
    }
    if (tid < 64) {
      float s = csred[0][tid] + csred[1][tid] + csred[2][tid] + csred[3][tid];
      partial[kt * 3072 + mat * DD + nt * 64 + tid] = s;   // [16][3072]
    }
  }
}

// ---------------- gemm body (v15): 128x128 tile + inlined column stats ------
__device__ __forceinline__ void gemm_body(
    int bx, int by, int mat, unsigned char* shmem,
    const unsigned short* __restrict__ Xhi, const unsigned short* __restrict__ Xlo,
    const unsigned short* __restrict__ ZThi, const unsigned short* __restrict__ ZTlo,
    const float* __restrict__ partial,
    const float* __restrict__ rq, const float* __restrict__ rk, const float* __restrict__ rv,
    const float* __restrict__ cx2,
    unsigned short* __restrict__ Qhi, unsigned short* __restrict__ Qlo,
    unsigned short* __restrict__ Khi, unsigned short* __restrict__ Klo,
    unsigned short* __restrict__ GThi, unsigned short* __restrict__ GTlo,
    float* __restrict__ q2, float* __restrict__ k2, float* __restrict__ gm1)
{
  unsigned short* Sbuf = (unsigned short*)shmem;

  float* Stat = (mat == 0) ? q2 : ((mat == 1) ? k2 : gm1);
  unsigned short* Bh = (mat == 0) ? Qhi : Khi;
  unsigned short* Bl = (mat == 0) ? Qlo : Klo;

  const int n0 = bx * 128;
  const int m0 = by * 128;
  const int tid = threadIdx.x;
  const int wave = tid >> 6, lane = tid & 63;
  const int tx = lane & 15, quad = lane >> 4;
  const int wrow = wave >> 1;                // rows [64*wrow, +64)
  const int wcol = wave & 1;                 // cols [64*wcol, +64) = head wcol

  const int l4r = lane >> 2;
  const int l4c = 8 * (((lane & 3) - (l4r >> 1)) & 3);
  const unsigned short* abase =
      (wave == 0) ? Xhi : (wave == 1) ? Xlo : (wave == 2) ? ZThi : ZTlo;
  const size_t rowbase = (wave < 2) ? (size_t)m0 : (size_t)(mat * DD + n0);
  const unsigned short* P[8];
  #pragma unroll
  for (int i = 0; i < 8; ++i)
    P[i] = abase + (rowbase + i * 16 + l4r) * DD + l4c;
  const int ldsw = 4096 * wave;              // wave's 8KB region within a buffer

  const int koff = 8 * ((quad + (tx >> 1)) & 3);

  const f32x4 z4 = {0.f, 0.f, 0.f, 0.f};
  f32x4 acc[4][4];
  #pragma unroll
  for (int mb = 0; mb < 4; ++mb)
    #pragma unroll
    for (int nb = 0; nb < 4; ++nb) acc[mb][nb] = z4;

  #pragma unroll
  for (int i = 0; i < 8; ++i) {
    async_copy16(P[i], Sbuf + ldsw + 512 * i);
    P[i] += 32;
  }

  for (int kt = 0; kt < 32; ++kt) {
    __syncthreads();                         // tile kt landed; buf[kt+1 &1] free
    if (kt < 31) {
      unsigned short* Bn = Sbuf + 16384 * ((kt + 1) & 1);
      #pragma unroll
      for (int i = 0; i < 8; ++i) {
        async_copy16(P[i], Bn + ldsw + 512 * i);
        P[i] += 32;
      }
    }
    const unsigned short* Bc = Sbuf + 16384 * (kt & 1);

    bf16x8 a_h[4], a_l[4];
    #pragma unroll
    for (int mb = 0; mb < 4; ++mb) {
      const int ar = 64 * wrow + 16 * mb + tx;
      a_h[mb] = *(const bf16x8*)&Bc[ar * 32 + koff];
      a_l[mb] = *(const bf16x8*)&Bc[4096 + ar * 32 + koff];
    }
    #pragma unroll
    for (int nb = 0; nb < 4; ++nb) {
      const int br = 64 * wcol + 16 * nb + tx;
      bf16x8 b_h = *(const bf16x8*)&Bc[8192 + br * 32 + koff];
      bf16x8 b_l = *(const bf16x8*)&Bc[12288 + br * 32 + koff];
      #pragma unroll
      for (int mb = 0; mb < 4; ++mb)
        acc[mb][nb] = __builtin_amdgcn_mfma_f32_16x16x32_bf16(a_h[mb], b_h, acc[mb][nb], 0, 0, 0);
      #pragma unroll
      for (int mb = 0; mb < 4; ++mb)
        acc[mb][nb] = __builtin_amdgcn_mfma_f32_16x16x32_bf16(a_h[mb], b_l, acc[mb][nb], 0, 0, 0);
      #pragma unroll
      for (int mb = 0; mb < 4; ++mb)
        acc[mb][nb] = __builtin_amdgcn_mfma_f32_16x16x32_bf16(a_l[mb], b_h, acc[mb][nb], 0, 0, 0);
    }
  }

  // ---- inlined column stats (was colstats_finalize_kernel) ----
  float acolv[4], bcolv[4], scolv[4];
  {
    const float* rarr = (mat == 0) ? rq : ((mat == 1) ? rk : rv);
    #pragma unroll
    for (int nb = 0; nb < 4; ++nb) {
      const int c = n0 + 64 * wcol + 16 * nb + tx;
      const int colg = mat * DD + c;
      float s = 0.f;
      #pragma unroll
      for (int rc = 0; rc < 16; ++rc) s += partial[rc * 3072 + colg];
      const float n = fmaxf(sqrtf(s), 1e-15f);
      const float rr2 = 2.0f * rarr[c];
      acolv[nb] = 2.0f * coshf(rr2) / n;
      bcolv[nb] = sinhf(rr2);
      scolv[nb] = 2.0f * n;
    }
  }

  const int head = bx * 2 + wcol;
  unsigned* Tr = (unsigned*)shmem;           // 2*128*65 unsigned (mat==2 only)
  if (mat == 2) __syncthreads();             // all waves done with Sbuf before reuse

  #pragma unroll
  for (int mb = 0; mb < 4; ++mb) {
    #pragma unroll
    for (int r = 0; r < 4; ++r) {
      const int sl = 64 * wrow + 16 * mb + 4 * quad + r;
      const int row = m0 + sl;
      const float c2 = cx2[row];
      const float inv = 1.0f / fmaxf(1.0f - c2, 1e-15f);
      const float onec = 1.0f + c2;
      float yv[4];
      #pragma unroll
      for (int nb = 0; nb < 4; ++nb) {
        const float accv = acc[mb][nb][r];
        const float u = fmaf(accv, acolv[nb], -(onec * bcolv[nb])) * inv;
        const float a = fabsf(u);
        const float t = a + sqrtf(fmaf(a, a, 1.0f));
        const float p = __builtin_amdgcn_exp2f(scolv[nb] * __builtin_amdgcn_logf(t));
        float y = 0.5f * (p - __builtin_amdgcn_rcpf(p));
        yv[nb] = copysignf(y, u);
      }
      const int b = row >> 10, s = row & 1023;
      float n2 = 0.f;
      #pragma unroll
      for (int j = 0; j < 4; ++j) n2 = fmaf(yv[j], yv[j], n2);
      n2 = xor_sum16(n2);
      float n = fmaxf(sqrtf(n2), 1e-15f);
      float s1 = (n > MAXN) ? (MAXN / n) : 1.0f;      // project #1
      n2 = n2 * s1 * s1;
      float f = 1.0f / (1.0f + sqrtf(1.0f + n2));     // exp-map scaling
      float fs = s1 * f;
      n2 = n2 * f * f;
      float nb2 = fmaxf(sqrtf(n2), 1e-15f);
      float s2f = (nb2 > MAXN) ? (MAXN / nb2) : 1.0f; // project #2
      fs *= s2f;
      n2 = n2 * s2f * s2f;

      const size_t bh = (size_t)(b * NH + head);
      const size_t outbase = (bh * SS + s) * DH;
      if (mat == 2) {
        const float gamma = 2.0f / fmaxf(1.0f - n2, 1e-15f);
        #pragma unroll
        for (int j = 0; j < 4; ++j) {
          const float v = yv[j] * fs * gamma;
          const unsigned short hi = f2bf(v);
          const unsigned short lo = f2bf(v - bf2f(hi));
          Tr[(wcol * 128 + sl) * 65 + 16 * j + tx] = ((unsigned)lo << 16) | (unsigned)hi;
        }
        if (tx == 0) Stat[bh * SS + s] = gamma - 1.0f;
      } else {
        #pragma unroll
        for (int j = 0; j < 4; ++j) {
          const float v = yv[j] * fs;
          const unsigned short hi = f2bf(v);
          const unsigned short lo = f2bf(v - bf2f(hi));
          Bh[outbase + 16 * j + tx] = hi;
          Bl[outbase + 16 * j + tx] = lo;
        }
        if (tx == 0) Stat[bh * SS + s] = n2;
      }
    }
  }

  if (mat == 2) {                            // cooperative transposed writeout
    __syncthreads();
    const int bb = m0 >> 10, sbase = m0 & 1023;
    #pragma unroll
    for (int i = 0; i < 4; ++i) {
      const int task = tid + 256 * i;        // 1024 tasks: 128 (h,dh) rows x 8 s-chunks
      const int rowid = task >> 3;
      const int hh = rowid >> 6, dh = rowid & 63;
      const int sc = (task & 7) * 16;
      unsigned short hbuf[16] __attribute__((aligned(16)));
      unsigned short lbuf[16] __attribute__((aligned(16)));
      #pragma unroll
      for (int s = 0; s < 16; ++s) {
        unsigned u = Tr[(hh * 128 + sc + s) * 65 + dh];
        hbuf[s] = (unsigned short)(u & 0xFFFFu);
        lbuf[s] = (unsigned short)(u >> 16);
      }
      const int hg = bx * 2 + hh;
      const size_t ob = (((size_t)(bb * NH + hg)) * DH + dh) * SS + sbase + sc;
      *(uint4*)(GThi + ob)     = *(uint4*)&hbuf[0];
      *(uint4*)(GThi + ob + 8) = *(uint4*)&hbuf[8];
      *(uint4*)(GTlo + ob)     = *(uint4*)&lbuf[0];
      *(uint4*)(GTlo + ob + 8) = *(uint4*)&lbuf[8];
    }
  }
}

// ---------------- flash body (v14, unchanged math) ----------------
// LDS layout inside shmem (halfword offsets): Ksh 0, Ksl 4096, Gsh 8192,
// Gsl 12288, Psh 16384, Psl 18944; floats at byte 43008. Total 44032 B.
__device__ __forceinline__ void flash_body(
    int h, int qt, int b, unsigned char* shmem,
    const unsigned short* __restrict__ Qhi, const unsigned short* __restrict__ Qlo,
    const unsigned short* __restrict__ Khi, const unsigned short* __restrict__ Klo,
    const unsigned short* __restrict__ GThi, const unsigned short* __restrict__ GTlo,
    const float* __restrict__ q2a, const float* __restrict__ k2a, const float* __restrict__ gm1a,
    const float* __restrict__ mask, float* __restrict__ out)
{
  unsigned short* S16 = (unsigned short*)shmem;
  unsigned short* Ksh = S16;                 // [2][2048]
  unsigned short* Ksl = S16 + 4096;
  unsigned short* Gsh = S16 + 8192;
  unsigned short* Gsl = S16 + 12288;
  unsigned short* Psh = S16 + 16384;         // 64*40
  unsigned short* Psl = S16 + 18944;
  float* fst  = (float*)(shmem + 43008);
  float* k2s  = fst;                         // [2][32]
  float* ik2s = fst + 64;
  float* gm1s = fst + 128;
  float* ems  = fst + 192;

  const int bh = b * NH + h;
  const int tid = threadIdx.x;
  const int wave = tid >> 6, lane = tid & 63;
  const int tx = lane & 15, quad = lane >> 4;
  const int r0 = qt * 64;

  bf16x8 qa_h[2], qa_l[2];
  {
    const size_t qoff = ((size_t)bh * SS + r0 + 16 * wave + tx) * DH;
    #pragma unroll
    for (int kc = 0; kc < 2; ++kc) {
      qa_h[kc] = *(const bf16x8*)(Qhi + qoff + 32 * kc + 8 * quad);
      qa_l[kc] = *(const bf16x8*)(Qlo + qoff + 32 * kc + 8 * quad);
    }
  }
  float q2r[4], iq2[4];
  #pragma unroll
  for (int r = 0; r < 4; ++r) {
    q2r[r] = q2a[(size_t)bh * SS + r0 + 16 * wave + 4 * quad + r];
    iq2[r] = 2.0f / fmaxf(1.0f - q2r[r], 1e-15f);
  }

  const f32x4 zero4 = {0.f, 0.f, 0.f, 0.f};
  f32x4 oacc[4] = {zero4, zero4, zero4, zero4};
  float dden[4] = {0.f, 0.f, 0.f, 0.f};

  const size_t kbase = (size_t)bh * SS * DH;   // K arrays: [key][dh]
  const size_t gbase = (size_t)bh * DH * SS;   // GT arrays: [dh][key]

  const unsigned short* sArr =
      (wave == 0) ? Khi : (wave == 1) ? Klo : (wave == 2) ? GThi : GTlo;
  const unsigned short* sBase = sArr + ((wave < 2) ? kbase : gbase);
  const int tAdv = (wave < 2) ? 32 * DH : 32;   // per-tile source advance (elems)
  int srcoff[4];
  if (wave < 2) {
    #pragma unroll
    for (int i = 0; i < 4; ++i) {
      const int r = 8 * i + (lane >> 3);
      srcoff[i] = r * DH + 8 * (((lane & 7) - r) & 7);
    }
  } else {
    #pragma unroll
    for (int i = 0; i < 4; ++i) {
      const int r = 16 * i + (lane >> 2);
      srcoff[i] = r * SS + 8 * (((lane & 3) - r) & 3);
    }
  }
  unsigned short* ldsDst[2];
  ldsDst[0] = (wave == 0) ? Ksh : (wave == 1) ? Ksl : (wave == 2) ? Gsh : Gsl;
  ldsDst[1] = ldsDst[0] + 2048;

  float s_k2 = 0.f, s_gm1 = 0.f, s_ms = 0.f;

  {
    const unsigned short* s = sBase;
    #pragma unroll
    for (int i = 0; i < 4; ++i) async_copy16(s + srcoff[i], ldsDst[0] + i * 512);
  }
  if (tid < 32) {
    s_k2  = k2a[(size_t)bh * SS + tid];
    s_gm1 = gm1a[(size_t)bh * SS + tid];
    s_ms  = mask[(size_t)b * SS + tid];
    k2s[tid]  = s_k2;
    ik2s[tid] = 1.0f / fmaxf(1.0f - s_k2, 1e-15f);
    gm1s[tid] = s_gm1;
    ems[tid]  = __expf(s_ms);
    s_k2  = k2a[(size_t)bh * SS + 32 + tid];
    s_gm1 = gm1a[(size_t)bh * SS + 32 + tid];
    s_ms  = mask[(size_t)b * SS + 32 + tid];
  }

  for (int kt = 0; kt < 32; ++kt) {
    __syncthreads();                         // tile kt + stats[kt&1] ready
    if (kt < 31) {
      const int nbuf = (kt + 1) & 1;
      const unsigned short* s = sBase + (size_t)(kt + 1) * tAdv;
      #pragma unroll
      for (int i = 0; i < 4; ++i) async_copy16(s + srcoff[i], ldsDst[nbuf] + i * 512);
      if (tid < 32) {
        k2s[nbuf * 32 + tid]  = s_k2;
        ik2s[nbuf * 32 + tid] = 1.0f / fmaxf(1.0f - s_k2, 1e-15f);
        gm1s[nbuf * 32 + tid] = s_gm1;
        ems[nbuf * 32 + tid]  = __expf(s_ms);
        if (kt < 30) {
          const int t2 = (kt + 2) * 32;
          s_k2  = k2a[(size_t)bh * SS + t2 + tid];
          s_gm1 = gm1a[(size_t)bh * SS + t2 + tid];
          s_ms  = mask[(size_t)b * SS + t2 + tid];
        }
      }
    }
    const int cb = kt & 1;

    // QK^T: S[64 q][32 key], K-dim = dh (2 kc steps)
    f32x4 sacc[2] = {zero4, zero4};
    #pragma unroll
    for (int kc = 0; kc < 2; ++kc) {
      #pragma unroll
      for (int nb = 0; nb < 2; ++nb) {
        const int row = 16 * nb + tx;
        const int off = row * 64 + 8 * (((4 * kc + quad) + row) & 7);
        bf16x8 kh = *(const bf16x8*)&Ksh[cb * 2048 + off];
        bf16x8 kl = *(const bf16x8*)&Ksl[cb * 2048 + off];
        sacc[nb] = __builtin_amdgcn_mfma_f32_16x16x32_bf16(qa_h[kc], kh, sacc[nb], 0, 0, 0);
        sacc[nb] = __builtin_amdgcn_mfma_f32_16x16x32_bf16(qa_h[kc], kl, sacc[nb], 0, 0, 0);
        sacc[nb] = __builtin_amdgcn_mfma_f32_16x16x32_bf16(qa_l[kc], kh, sacc[nb], 0, 0, 0);
      }
    }

    // hyperbolic weights
    float pb[4][2];
    #pragma unroll
    for (int nb = 0; nb < 2; ++nb) {
      const int key = 16 * nb + tx;
      const float k2v = k2s[cb * 32 + key], ikv = ik2s[cb * 32 + key];
      const float emv = ems[cb * 32 + key], gmv = gm1s[cb * 32 + key];
      #pragma unroll
      for (int r = 0; r < 4; ++r) {
        float sv = sacc[nb][r];
        float num = fmaxf(fmaf(-2.0f, sv, q2r[r] + k2v), 1e-15f);
        float e = num * iq2[r] * ikv;
        float g = fmaf(e, e, e + e);
        float z = 1.0f + e + __builtin_amdgcn_sqrtf(g);
        float w = emv * __builtin_amdgcn_rcpf(z);
        pb[r][nb] = w;
        dden[r] = fmaf(w, gmv, dden[r]);
      }
    }

    // P -> LDS (wave-private rows), split-bf16
    #pragma unroll
    for (int r = 0; r < 4; ++r) {
      const int prow = 16 * wave + 4 * quad + r;
      #pragma unroll
      for (int nb = 0; nb < 2; ++nb) {
        float w = pb[r][nb];
        unsigned short hi = f2bf(w);
        unsigned short lo = f2bf(w - bf2f(hi));
        Psh[prow * 40 + 16 * nb + tx] = hi;
        Psl[prow * 40 + 16 * nb + tx] = lo;
      }
    }
    // PV: K-dim = 32 keys (single MFMA K), same-wave LDS RAW only
    bf16x8 ph = *(const bf16x8*)&Psh[(16 * wave + tx) * 40 + 8 * quad];
    bf16x8 pl = *(const bf16x8*)&Psl[(16 * wave + tx) * 40 + 8 * quad];
    #pragma unroll
    for (int nb = 0; nb < 4; ++nb) {
      const int row = 16 * nb + tx;
      const int off = row * 32 + 8 * ((quad + row) & 3);
      bf16x8 gh = *(const bf16x8*)&Gsh[cb * 2048 + off];
      bf16x8 gl = *(const bf16x8*)&Gsl[cb * 2048 + off];
      oacc[nb] = __builtin_amdgcn_mfma_f32_16x16x32_bf16(ph, gh, oacc[nb], 0, 0, 0);
      oacc[nb] = __builtin_amdgcn_mfma_f32_16x16x32_bf16(ph, gl, oacc[nb], 0, 0, 0);
      oacc[nb] = __builtin_amdgcn_mfma_f32_16x16x32_bf16(pl, gh, oacc[nb], 0, 0, 0);
    }
  }

  #pragma unroll
  for (int r = 0; r < 4; ++r) {
    float d = fmaxf(xor_sum16(dden[r]), 1e-10f);
    float invd = 1.0f / d;
    float tm[4]; float sq = 0.f;
    #pragma unroll
    for (int nb = 0; nb < 4; ++nb) { tm[nb] = oacc[nb][r] * invd; sq = fmaf(tm[nb], tm[nb], sq); }
    sq = xor_sum16(sq);
    const float f = 1.0f / (1.0f + sqrtf(fmaxf(1.0f - sq, 1e-15f)));
    const float n2 = sq * f * f;
    const float n = fmaxf(sqrtf(n2), 1e-15f);
    const float s2 = (n > MAXN) ? (MAXN / n) : 1.0f;
    const float fs = f * s2;
    const int qrow = r0 + 16 * wave + 4 * quad + r;
    #pragma unroll
    for (int nb = 0; nb < 4; ++nb)
      out[((size_t)(b * SS + qrow)) * DD + h * DH + 16 * nb + tx] = tm[nb] * fs;
  }
}

// ---------------- standalone kernels (fallback path) ----------------
__global__ __launch_bounds__(256, 2) void gemm_mfma_kernel(
    const unsigned short* __restrict__ Xhi, const unsigned short* __restrict__ Xlo,
    const unsigned short* __restrict__ ZThi, const unsigned short* __restrict__ ZTlo,
    const float* __restrict__ partial,
    const float* __restrict__ rq, const float* __restrict__ rk, const float* __restrict__ rv,
    const float* __restrict__ cx2,
    unsigned short* __restrict__ Qhi, unsigned short* __restrict__ Qlo,
    unsigned short* __restrict__ Khi, unsigned short* __restrict__ Klo,
    unsigned short* __restrict__ GThi, unsigned short* __restrict__ GTlo,
    float* __restrict__ q2, float* __restrict__ k2, float* __restrict__ gm1)
{
  __shared__ __align__(16) unsigned char shmem[66560];
  gemm_body(blockIdx.x, blockIdx.y, blockIdx.z, shmem,
            Xhi, Xlo, ZThi, ZTlo, partial, rq, rk, rv, cx2,
            Qhi, Qlo, Khi, Klo, GThi, GTlo, q2, k2, gm1);
}

__global__ __launch_bounds__(256) void flash_attn_kernel(
    const unsigned short* __restrict__ Qhi, const unsigned short* __restrict__ Qlo,
    const unsigned short* __restrict__ Khi, const unsigned short* __restrict__ Klo,
    const unsigned short* __restrict__ GThi, const unsigned short* __restrict__ GTlo,
    const float* __restrict__ q2a, const float* __restrict__ k2a, const float* __restrict__ gm1a,
    const float* __restrict__ mask, float* __restrict__ out)
{
  __shared__ __align__(16) unsigned char shmem[44032];
  flash_body(blockIdx.x, blockIdx.y, blockIdx.z, shmem,
             Qhi, Qlo, Khi, Klo, GThi, GTlo, q2a, k2a, gm1a, mask, out);
}

// ---------------- fused cooperative kernel (v15) ----------------
// 512 blocks, 2/CU (LDS 66560) = exactly co-resident. Blocks 0..383 run gemm
// (x=bid&7, y=(bid>>3)&15, mat=bid>>7 -> XCD = x%8, same as dim3(8,16,3));
// grid.sync(); all 512 run flash (h=bid&15 -> XCD = h%8, same as before).
// Removes one dispatch + the gemm->flash drain gap.
__global__ __launch_bounds__(256, 2) void gemm_flash_kernel(
    const unsigned short* __restrict__ Xhi, const unsigned short* __restrict__ Xlo,
    const unsigned short* __restrict__ ZThi, const unsigned short* __restrict__ ZTlo,
    const float* __restrict__ partial,
    const float* __restrict__ rq, const float* __restrict__ rk, const float* __restrict__ rv,
    const float* __restrict__ cx2,
    unsigned short* __restrict__ Qhi, unsigned short* __restrict__ Qlo,
    unsigned short* __restrict__ Khi, unsigned short* __restrict__ Klo,
    unsigned short* __restrict__ GThi, unsigned short* __restrict__ GTlo,
    float* __restrict__ q2, float* __restrict__ k2, float* __restrict__ gm1,
    const float* __restrict__ mask, float* __restrict__ out)
{
  __shared__ __align__(16) unsigned char shmem[66560];
  const int bid = blockIdx.x;

  if (bid < 384) {
    gemm_body(bid & 7, (bid >> 3) & 15, bid >> 7, shmem,
              Xhi, Xlo, ZThi, ZTlo, partial, rq, rk, rv, cx2,
              Qhi, Qlo, Khi, Klo, GThi, GTlo, q2, k2, gm1);
  }
  cg::this_grid().sync();
  flash_body(bid & 15, (bid >> 4) & 15, bid >> 8, shmem,
             Qhi, Qlo, Khi, Klo, GThi, GTlo, q2, k2, gm1, mask, out);
}

// ---------------- host ----------------
extern "C" void kernel_launch(void* const* d_in, const int* in_sizes, int n_in,
                              void* d_out, int out_size, void* d_ws, size_t ws_size,
                              hipStream_t stream) {
  const float* hs   = (const float*)d_in[0];
  const float* mask = (const float*)d_in[1];
  const float* qz   = (const float*)d_in[2];
  const float* qr   = (const float*)d_in[3];
  const float* kz   = (const float*)d_in[4];
  const float* kr   = (const float*)d_in[5];
  const float* vz   = (const float*)d_in[6];
  const float* vr   = (const float*)d_in[7];
  float* out = (float*)d_out;

  float* ws = (float*)d_ws;
  const size_t nQKV = (size_t)BB * NH * SS * DH;   // 2,097,152
  const size_t nStat = (size_t)BB * NH * SS;       // 32,768

  // fp32 region
  float* q2  = ws;
  float* k2  = q2 + nStat;
  float* gm1 = k2 + nStat;
  float* cx2 = gm1 + nStat;          // 2048
  float* partial = cx2 + 2048;       // 16 x 3072 col-sum partials (192 KB)

  // bf16 region (halfwords). gemm reads X/ZT while writing Q/K/GT -> all distinct.
  unsigned short* sb   = (unsigned short*)(partial + 16 * 3072);   // 16B-aligned
  unsigned short* Qhi  = sb;                  // 2M each
  unsigned short* Qlo  = Qhi + nQKV;
  unsigned short* Khi  = Qlo + nQKV;
  unsigned short* Klo  = Khi + nQKV;
  unsigned short* GThi = Klo + nQKV;
  unsigned short* GTlo = GThi + nQKV;
  unsigned short* Xhi  = GTlo + nQKV;
  unsigned short* Xlo  = Xhi + nQKV;
  unsigned short* ZThi = Xlo + nQKV;          // 3M each
  unsigned short* ZTlo = ZThi + 3 * (size_t)DD * DD;  // total ~44 MB

  prep_kernel<<<dim3(1792), 256, 0, stream>>>(
      hs, qz, kz, vz, cx2, partial, Xhi, Xlo, ZThi, ZTlo);

  // fused gemm+flash via cooperative launch; fall back to two launches.
  void* kargs[] = {
      (void*)&Xhi, (void*)&Xlo, (void*)&ZThi, (void*)&ZTlo, (void*)&partial,
      (void*)&qr, (void*)&kr, (void*)&vr, (void*)&cx2,
      (void*)&Qhi, (void*)&Qlo, (void*)&Khi, (void*)&Klo,
      (void*)&GThi, (void*)&GTlo, (void*)&q2, (void*)&k2, (void*)&gm1,
      (void*)&mask, (void*)&out};
  hipError_t e = hipLaunchCooperativeKernel(
      (const void*)gemm_flash_kernel, dim3(512), dim3(256), kargs, 0, stream);
  if (e != hipSuccess) {
    (void)hipGetLastError();   // clear sticky error
    gemm_mfma_kernel<<<dim3(8, 16, 3), 256, 0, stream>>>(
        Xhi, Xlo, ZThi, ZTlo, partial, qr, kr, vr, cx2,
        Qhi, Qlo, Khi, Klo, GThi, GTlo, q2, k2, gm1);
    flash_attn_kernel<<<dim3(NH, 16, BB), 256, 0, stream>>>(
        Qhi, Qlo, Khi, Klo, GThi, GTlo, q2, k2, gm1, mask, out);
  }
}

// Round 17
// 196.710 us; speedup vs baseline: 1.3941x; 1.3941x over previous
//
#include <hip/hip_runtime.h>
#include <math.h>

// Problem constants (C = RC = 1)
#define BB 2
#define SS 1024
#define DD 1024
#define NH 16
#define DH 64
#define MAXN 0.996f   // (1 - PROJ_EPS)/RC

typedef __attribute__((ext_vector_type(8))) short bf16x8;  // MFMA A/B frag (4 VGPRs)
typedef __attribute__((ext_vector_type(4))) float f32x4;   // MFMA C/D frag

__device__ __forceinline__ float xor_sum16(float v){
  v += __shfl_xor(v, 1, 64);
  v += __shfl_xor(v, 2, 64);
  v += __shfl_xor(v, 4, 64);
  v += __shfl_xor(v, 8, 64);
  return v;
}

__device__ __forceinline__ unsigned short f2bf(float x){
  unsigned u = __builtin_bit_cast(unsigned, x);
  unsigned r = u + 0x7FFFu + ((u >> 16) & 1u);   // RNE
  return (unsigned short)(r >> 16);
}
__device__ __forceinline__ float bf2f(unsigned short b){
  unsigned u = ((unsigned)b) << 16;
  return __builtin_bit_cast(float, u);
}

// async global->LDS DMA: per-lane 16B from g, landing at wave-uniform s + lane*16
__device__ __forceinline__ void async_copy16(const unsigned short* g, unsigned short* s){
  __builtin_amdgcn_global_load_lds(
      (const __attribute__((address_space(1))) unsigned int*)g,
      (__attribute__((address_space(3))) unsigned int*)s,
      16, 0, 0);
}

// ---------------- K1: fused prep (one launch) ----------------
// v13: col_stats folded into convert_zt (partial col-sums); stats finalization
// lives in the gemm epilogue (v15, VALIDATED round 13) - no finalize kernel.
// blocks [0,1024): convert_x (split-bf16) + fused per-row ||x||^2 (2 rows/block)
// blocks [1024,1792): convert_zt (z -> split-bf16 transposed ZT[mat][n][k]) + col-partials
__global__ __launch_bounds__(256) void prep_kernel(
    const float* __restrict__ hs,
    const float* __restrict__ zq, const float* __restrict__ zk, const float* __restrict__ zv,
    float* __restrict__ cx2, float* __restrict__ partial,
    unsigned short* __restrict__ Xhi, unsigned short* __restrict__ Xlo,
    unsigned short* __restrict__ ZThi, unsigned short* __restrict__ ZTlo)
{
  __shared__ unsigned shbuf[64 * 69];     // 17.6 KB, aliased per role
  __shared__ float csred[4][64];          // cross-wave col-sum reduce (convert_zt)
  const int bid = blockIdx.x;
  const int tid = threadIdx.x;

  if (bid < 1024) {
    // ---- convert_x + row ||x||^2 (rows 2b, 2b+1) ----
    const int b = bid;
    const size_t g0 = (size_t)b * 2048 + (size_t)tid * 8;
    float acc = 0.0f;
    #pragma unroll
    for (int h = 0; h < 2; ++h) {
      float4 v = *(const float4*)(hs + g0 + 4 * h);
      float a[4] = {v.x, v.y, v.z, v.w};
      ushort4 hv, lv;
      unsigned short* hp = (unsigned short*)&hv;
      unsigned short* lp = (unsigned short*)&lv;
      #pragma unroll
      for (int j = 0; j < 4; ++j) {
        acc = fmaf(a[j], a[j], acc);
        unsigned short hi = f2bf(a[j]);
        hp[j] = hi;
        lp[j] = f2bf(a[j] - bf2f(hi));
      }
      *(ushort4*)(Xhi + g0 + 4 * h) = hv;
      *(ushort4*)(Xlo + g0 + 4 * h) = lv;
    }
    #pragma unroll
    for (int m = 1; m < 64; m <<= 1) acc += __shfl_xor(acc, m, 64);
    float* red = (float*)shbuf;
    const int wave = tid >> 6, lane = tid & 63;
    if (lane == 0) red[wave] = acc;
    __syncthreads();
    if (tid == 0)   cx2[2 * b]     = red[0] + red[1];
    if (tid == 128) cx2[2 * b + 1] = red[2] + red[3];
  } else {
    // ---- convert_zt + column-sum partials ----
    const int b2 = bid - 1024;
    const int kt = b2 & 15, nt = (b2 >> 4) & 15, mat = b2 >> 8;
    const float* z = (mat == 0) ? zq : ((mat == 1) ? zk : zv);
    const int wave = tid >> 6, lane = tid & 63;
    unsigned (*T)[69] = (unsigned(*)[69])shbuf;
    float cs[4] = {0.f, 0.f, 0.f, 0.f};
    #pragma unroll
    for (int i = 0; i < 4; ++i) {
      const int g = tid + 256 * i;
      const int kr = g >> 4, nc = (g & 15) * 4;   // nc fixed per thread
      float4 v = *(const float4*)(z + (size_t)(kt * 64 + kr) * DD + nt * 64 + nc);
      float a[4] = {v.x, v.y, v.z, v.w};
      #pragma unroll
      for (int j = 0; j < 4; ++j) {
        cs[j] = fmaf(a[j], a[j], cs[j]);
        unsigned short hi = f2bf(a[j]);
        unsigned short lo = f2bf(a[j] - bf2f(hi));
        T[kr][nc + j] = ((unsigned)lo << 16) | (unsigned)hi;
      }
    }
    // intra-wave reduce over row-groups (lanes l, l^16, l^32, l^48 share cols)
    #pragma unroll
    for (int j = 0; j < 4; ++j) {
      cs[j] += __shfl_xor(cs[j], 16, 64);
      cs[j] += __shfl_xor(cs[j], 32, 64);
    }
    if (lane < 16) {
      #pragma unroll
      for (int j = 0; j < 4; ++j) csred[wave][lane * 4 + j] = cs[j];
    }
    __syncthreads();
    #pragma unroll
    for (int i = 0; i < 4; ++i) {
      const int g = tid + 256 * i;
      const int nr = g >> 4, kc = (g & 15) * 4;
      ushort4 hv, lv;
      unsigned short* hp = (unsigned short*)&hv;
      unsigned short* lp = (unsigned short*)&lv;
      #pragma unroll
      for (int j = 0; j < 4; ++j) {
        unsigned u = T[kc + j][nr];
        hp[j] = (unsigned short)(u & 0xFFFFu);
        lp[j] = (unsigned short)(u >> 16);
      }
      const size_t ob = ((size_t)mat * DD + nt * 64 + nr) * DD + kt * 64 + kc;
      *(ushort4*)(ZThi + ob) = hv;
      *(ushort4*)(ZTlo + ob) = lv;
    }
    if (tid < 64) {
      float s = csred[0][tid] + csred[1][tid] + csred[2][tid] + csred[3][tid];
      partial[kt * 3072 + mat * DD + nt * 64 + tid] = s;   // [16][3072]
    }
  }
}

// ---------------- K2: split-bf16 MFMA GEMM + Poincare epilogue (v16) --------
// v15's inlined column stats kept (validated); cooperative fusion REVERTED
// (round 13: fused kernel = 179us vs 66+~39 separate). 128x128 tile, wave tile
// 64x64, BK=32, 2-buffer barrier->issue-next->compute.
__global__ __launch_bounds__(256, 2) void gemm_mfma_kernel(
    const unsigned short* __restrict__ Xhi, const unsigned short* __restrict__ Xlo,
    const unsigned short* __restrict__ ZThi, const unsigned short* __restrict__ ZTlo,
    const float* __restrict__ partial,
    const float* __restrict__ rq, const float* __restrict__ rk, const float* __restrict__ rv,
    const float* __restrict__ cx2,
    unsigned short* __restrict__ Qhi, unsigned short* __restrict__ Qlo,
    unsigned short* __restrict__ Khi, unsigned short* __restrict__ Klo,
    unsigned short* __restrict__ GThi, unsigned short* __restrict__ GTlo,
    float* __restrict__ q2, float* __restrict__ k2, float* __restrict__ gm1)
{
  __shared__ __align__(16) unsigned char shmem[66560];   // 65 KB -> 2 blocks/CU
  unsigned short* Sbuf = (unsigned short*)shmem;

  const int mat = blockIdx.z;
  float* Stat = (mat == 0) ? q2 : ((mat == 1) ? k2 : gm1);
  unsigned short* Bh = (mat == 0) ? Qhi : Khi;
  unsigned short* Bl = (mat == 0) ? Qlo : Klo;

  const int n0 = blockIdx.x * 128;
  const int m0 = blockIdx.y * 128;
  const int tid = threadIdx.x;
  const int wave = tid >> 6, lane = tid & 63;
  const int tx = lane & 15, quad = lane >> 4;
  const int wrow = wave >> 1;                // rows [64*wrow, +64)
  const int wcol = wave & 1;                 // cols [64*wcol, +64) = head wcol

  const int l4r = lane >> 2;
  const int l4c = 8 * (((lane & 3) - (l4r >> 1)) & 3);
  const unsigned short* abase =
      (wave == 0) ? Xhi : (wave == 1) ? Xlo : (wave == 2) ? ZThi : ZTlo;
  const size_t rowbase = (wave < 2) ? (size_t)m0 : (size_t)(mat * DD + n0);
  const unsigned short* P[8];
  #pragma unroll
  for (int i = 0; i < 8; ++i)
    P[i] = abase + (rowbase + i * 16 + l4r) * DD + l4c;
  const int ldsw = 4096 * wave;              // wave's 8KB region within a buffer

  const int koff = 8 * ((quad + (tx >> 1)) & 3);

  const f32x4 z4 = {0.f, 0.f, 0.f, 0.f};
  f32x4 acc[4][4];
  #pragma unroll
  for (int mb = 0; mb < 4; ++mb)
    #pragma unroll
    for (int nb = 0; nb < 4; ++nb) acc[mb][nb] = z4;

  #pragma unroll
  for (int i = 0; i < 8; ++i) {
    async_copy16(P[i], Sbuf + ldsw + 512 * i);
    P[i] += 32;
  }

  for (int kt = 0; kt < 32; ++kt) {
    __syncthreads();                         // tile kt landed; buf[kt+1 &1] free
    if (kt < 31) {
      unsigned short* Bn = Sbuf + 16384 * ((kt + 1) & 1);
      #pragma unroll
      for (int i = 0; i < 8; ++i) {
        async_copy16(P[i], Bn + ldsw + 512 * i);
        P[i] += 32;
      }
    }
    const unsigned short* Bc = Sbuf + 16384 * (kt & 1);

    bf16x8 a_h[4], a_l[4];
    #pragma unroll
    for (int mb = 0; mb < 4; ++mb) {
      const int ar = 64 * wrow + 16 * mb + tx;
      a_h[mb] = *(const bf16x8*)&Bc[ar * 32 + koff];
      a_l[mb] = *(const bf16x8*)&Bc[4096 + ar * 32 + koff];
    }
    #pragma unroll
    for (int nb = 0; nb < 4; ++nb) {
      const int br = 64 * wcol + 16 * nb + tx;
      bf16x8 b_h = *(const bf16x8*)&Bc[8192 + br * 32 + koff];
      bf16x8 b_l = *(const bf16x8*)&Bc[12288 + br * 32 + koff];
      #pragma unroll
      for (int mb = 0; mb < 4; ++mb)
        acc[mb][nb] = __builtin_amdgcn_mfma_f32_16x16x32_bf16(a_h[mb], b_h, acc[mb][nb], 0, 0, 0);
      #pragma unroll
      for (int mb = 0; mb < 4; ++mb)
        acc[mb][nb] = __builtin_amdgcn_mfma_f32_16x16x32_bf16(a_h[mb], b_l, acc[mb][nb], 0, 0, 0);
      #pragma unroll
      for (int mb = 0; mb < 4; ++mb)
        acc[mb][nb] = __builtin_amdgcn_mfma_f32_16x16x32_bf16(a_l[mb], b_h, acc[mb][nb], 0, 0, 0);
    }
  }

  // ---- inlined column stats (validated round 13) ----
  float acolv[4], bcolv[4], scolv[4];
  {
    const float* rarr = (mat == 0) ? rq : ((mat == 1) ? rk : rv);
    #pragma unroll
    for (int nb = 0; nb < 4; ++nb) {
      const int c = n0 + 64 * wcol + 16 * nb + tx;
      const int colg = mat * DD + c;
      float s = 0.f;
      #pragma unroll
      for (int rc = 0; rc < 16; ++rc) s += partial[rc * 3072 + colg];
      const float n = fmaxf(sqrtf(s), 1e-15f);
      const float rr2 = 2.0f * rarr[c];
      acolv[nb] = 2.0f * coshf(rr2) / n;
      bcolv[nb] = sinhf(rr2);
      scolv[nb] = 2.0f * n;
    }
  }

  const int head = blockIdx.x * 2 + wcol;
  unsigned* Tr = (unsigned*)shmem;           // 2*128*65 unsigned (mat==2 only)
  if (mat == 2) __syncthreads();             // all waves done with Sbuf before reuse

  #pragma unroll
  for (int mb = 0; mb < 4; ++mb) {
    #pragma unroll
    for (int r = 0; r < 4; ++r) {
      const int sl = 64 * wrow + 16 * mb + 4 * quad + r;
      const int row = m0 + sl;
      const float c2 = cx2[row];
      const float inv = 1.0f / fmaxf(1.0f - c2, 1e-15f);
      const float onec = 1.0f + c2;
      float yv[4];
      #pragma unroll
      for (int nb = 0; nb < 4; ++nb) {
        const float accv = acc[mb][nb][r];
        const float u = fmaf(accv, acolv[nb], -(onec * bcolv[nb])) * inv;
        const float a = fabsf(u);
        const float t = a + sqrtf(fmaf(a, a, 1.0f));
        const float p = __builtin_amdgcn_exp2f(scolv[nb] * __builtin_amdgcn_logf(t));
        float y = 0.5f * (p - __builtin_amdgcn_rcpf(p));
        yv[nb] = copysignf(y, u);
      }
      const int b = row >> 10, s = row & 1023;
      float n2 = 0.f;
      #pragma unroll
      for (int j = 0; j < 4; ++j) n2 = fmaf(yv[j], yv[j], n2);
      n2 = xor_sum16(n2);
      float n = fmaxf(sqrtf(n2), 1e-15f);
      float s1 = (n > MAXN) ? (MAXN / n) : 1.0f;      // project #1
      n2 = n2 * s1 * s1;
      float f = 1.0f / (1.0f + sqrtf(1.0f + n2));     // exp-map scaling
      float fs = s1 * f;
      n2 = n2 * f * f;
      float nb2 = fmaxf(sqrtf(n2), 1e-15f);
      float s2f = (nb2 > MAXN) ? (MAXN / nb2) : 1.0f; // project #2
      fs *= s2f;
      n2 = n2 * s2f * s2f;

      const size_t bh = (size_t)(b * NH + head);
      const size_t outbase = (bh * SS + s) * DH;
      if (mat == 2) {
        const float gamma = 2.0f / fmaxf(1.0f - n2, 1e-15f);
        #pragma unroll
        for (int j = 0; j < 4; ++j) {
          const float v = yv[j] * fs * gamma;
          const unsigned short hi = f2bf(v);
          const unsigned short lo = f2bf(v - bf2f(hi));
          Tr[(wcol * 128 + sl) * 65 + 16 * j + tx] = ((unsigned)lo << 16) | (unsigned)hi;
        }
        if (tx == 0) Stat[bh * SS + s] = gamma - 1.0f;
      } else {
        #pragma unroll
        for (int j = 0; j < 4; ++j) {
          const float v = yv[j] * fs;
          const unsigned short hi = f2bf(v);
          const unsigned short lo = f2bf(v - bf2f(hi));
          Bh[outbase + 16 * j + tx] = hi;
          Bl[outbase + 16 * j + tx] = lo;
        }
        if (tx == 0) Stat[bh * SS + s] = n2;
      }
    }
  }

  if (mat == 2) {                            // cooperative transposed writeout
    __syncthreads();
    const int bb = m0 >> 10, sbase = m0 & 1023;
    #pragma unroll
    for (int i = 0; i < 4; ++i) {
      const int task = tid + 256 * i;        // 1024 tasks: 128 (h,dh) rows x 8 s-chunks
      const int rowid = task >> 3;
      const int hh = rowid >> 6, dh = rowid & 63;
      const int sc = (task & 7) * 16;
      unsigned short hbuf[16] __attribute__((aligned(16)));
      unsigned short lbuf[16] __attribute__((aligned(16)));
      #pragma unroll
      for (int s = 0; s < 16; ++s) {
        unsigned u = Tr[(hh * 128 + sc + s) * 65 + dh];
        hbuf[s] = (unsigned short)(u & 0xFFFFu);
        lbuf[s] = (unsigned short)(u >> 16);
      }
      const int hg = blockIdx.x * 2 + hh;
      const size_t ob = (((size_t)(bb * NH + hg)) * DH + dh) * SS + sbase + sc;
      *(uint4*)(GThi + ob)     = *(uint4*)&hbuf[0];
      *(uint4*)(GThi + ob + 8) = *(uint4*)&hbuf[8];
      *(uint4*)(GTlo + ob)     = *(uint4*)&lbuf[0];
      *(uint4*)(GTlo + ob + 8) = *(uint4*)&lbuf[8];
    }
  }
}

// ---------------- K3: MFMA flash-style hyperbolic attention (v14) ----------
// DMA-staged, 2-buffer, ONE barrier/iter (validated round 8/13). KVBLK=32.
__global__ __launch_bounds__(256) void flash_attn_kernel(
    const unsigned short* __restrict__ Qhi, const unsigned short* __restrict__ Qlo,
    const unsigned short* __restrict__ Khi, const unsigned short* __restrict__ Klo,
    const unsigned short* __restrict__ GThi, const unsigned short* __restrict__ GTlo,
    const float* __restrict__ q2a, const float* __restrict__ k2a, const float* __restrict__ gm1a,
    const float* __restrict__ mask, float* __restrict__ out)
{
  __shared__ unsigned short Ksh[2][2048];    // [buf][32 key-rows x 64 dh] swizzled
  __shared__ unsigned short Ksl[2][2048];
  __shared__ unsigned short Gsh[2][2048];    // [buf][64 dh-rows x 32 keys] swizzled
  __shared__ unsigned short Gsl[2][2048];
  __shared__ unsigned short Psh[64 * 40];    // P rows (wave-private 16-row bands)
  __shared__ unsigned short Psl[64 * 40];
  __shared__ float k2s[2][32], ik2s[2][32], gm1s[2][32], ems[2][32];

  const int h = blockIdx.x, qt = blockIdx.y, b = blockIdx.z;   // XCD = h%8
  const int bh = b * NH + h;
  const int tid = threadIdx.x;
  const int wave = tid >> 6, lane = tid & 63;
  const int tx = lane & 15, quad = lane >> 4;
  const int r0 = qt * 64;

  bf16x8 qa_h[2], qa_l[2];
  {
    const size_t qoff = ((size_t)bh * SS + r0 + 16 * wave + tx) * DH;
    #pragma unroll
    for (int kc = 0; kc < 2; ++kc) {
      qa_h[kc] = *(const bf16x8*)(Qhi + qoff + 32 * kc + 8 * quad);
      qa_l[kc] = *(const bf16x8*)(Qlo + qoff + 32 * kc + 8 * quad);
    }
  }
  float q2r[4], iq2[4];
  #pragma unroll
  for (int r = 0; r < 4; ++r) {
    q2r[r] = q2a[(size_t)bh * SS + r0 + 16 * wave + 4 * quad + r];
    iq2[r] = 2.0f / fmaxf(1.0f - q2r[r], 1e-15f);
  }

  const f32x4 zero4 = {0.f, 0.f, 0.f, 0.f};
  f32x4 oacc[4] = {zero4, zero4, zero4, zero4};
  float dden[4] = {0.f, 0.f, 0.f, 0.f};

  const size_t kbase = (size_t)bh * SS * DH;   // K arrays: [key][dh]
  const size_t gbase = (size_t)bh * DH * SS;   // GT arrays: [dh][key]

  const unsigned short* sArr =
      (wave == 0) ? Khi : (wave == 1) ? Klo : (wave == 2) ? GThi : GTlo;
  const unsigned short* sBase = sArr + ((wave < 2) ? kbase : gbase);
  const int tAdv = (wave < 2) ? 32 * DH : 32;   // per-tile source advance (elems)
  int srcoff[4];
  if (wave < 2) {
    #pragma unroll
    for (int i = 0; i < 4; ++i) {
      const int r = 8 * i + (lane >> 3);
      srcoff[i] = r * DH + 8 * (((lane & 7) - r) & 7);
    }
  } else {
    #pragma unroll
    for (int i = 0; i < 4; ++i) {
      const int r = 16 * i + (lane >> 2);
      srcoff[i] = r * SS + 8 * (((lane & 3) - r) & 3);
    }
  }
  unsigned short* ldsDst[2];
  ldsDst[0] = (wave == 0) ? Ksh[0] : (wave == 1) ? Ksl[0] : (wave == 2) ? Gsh[0] : Gsl[0];
  ldsDst[1] = (wave == 0) ? Ksh[1] : (wave == 1) ? Ksl[1] : (wave == 2) ? Gsh[1] : Gsl[1];

  float s_k2 = 0.f, s_gm1 = 0.f, s_ms = 0.f;

  {
    const unsigned short* s = sBase;
    #pragma unroll
    for (int i = 0; i < 4; ++i) async_copy16(s + srcoff[i], ldsDst[0] + i * 512);
  }
  if (tid < 32) {
    s_k2  = k2a[(size_t)bh * SS + tid];
    s_gm1 = gm1a[(size_t)bh * SS + tid];
    s_ms  = mask[(size_t)b * SS + tid];
    k2s[0][tid]  = s_k2;
    ik2s[0][tid] = 1.0f / fmaxf(1.0f - s_k2, 1e-15f);
    gm1s[0][tid] = s_gm1;
    ems[0][tid]  = __expf(s_ms);
    s_k2  = k2a[(size_t)bh * SS + 32 + tid];
    s_gm1 = gm1a[(size_t)bh * SS + 32 + tid];
    s_ms  = mask[(size_t)b * SS + 32 + tid];
  }

  for (int kt = 0; kt < 32; ++kt) {
    __syncthreads();                         // tile kt + stats[kt&1] ready
    if (kt < 31) {
      const int nbuf = (kt + 1) & 1;
      const unsigned short* s = sBase + (size_t)(kt + 1) * tAdv;
      #pragma unroll
      for (int i = 0; i < 4; ++i) async_copy16(s + srcoff[i], ldsDst[nbuf] + i * 512);
      if (tid < 32) {
        k2s[nbuf][tid]  = s_k2;
        ik2s[nbuf][tid] = 1.0f / fmaxf(1.0f - s_k2, 1e-15f);
        gm1s[nbuf][tid] = s_gm1;
        ems[nbuf][tid]  = __expf(s_ms);
        if (kt < 30) {
          const int t2 = (kt + 2) * 32;
          s_k2  = k2a[(size_t)bh * SS + t2 + tid];
          s_gm1 = gm1a[(size_t)bh * SS + t2 + tid];
          s_ms  = mask[(size_t)b * SS + t2 + tid];
        }
      }
    }
    const int cb = kt & 1;

    // QK^T: S[64 q][32 key], K-dim = dh (2 kc steps)
    f32x4 sacc[2] = {zero4, zero4};
    #pragma unroll
    for (int kc = 0; kc < 2; ++kc) {
      #pragma unroll
      for (int nb = 0; nb < 2; ++nb) {
        const int row = 16 * nb + tx;
        const int off = row * 64 + 8 * (((4 * kc + quad) + row) & 7);
        bf16x8 kh = *(const bf16x8*)&Ksh[cb][off];
        bf16x8 kl = *(const bf16x8*)&Ksl[cb][off];
        sacc[nb] = __builtin_amdgcn_mfma_f32_16x16x32_bf16(qa_h[kc], kh, sacc[nb], 0, 0, 0);
        sacc[nb] = __builtin_amdgcn_mfma_f32_16x16x32_bf16(qa_h[kc], kl, sacc[nb], 0, 0, 0);
        sacc[nb] = __builtin_amdgcn_mfma_f32_16x16x32_bf16(qa_l[kc], kh, sacc[nb], 0, 0, 0);
      }
    }

    // hyperbolic weights
    float pb[4][2];
    #pragma unroll
    for (int nb = 0; nb < 2; ++nb) {
      const int key = 16 * nb + tx;
      const float k2v = k2s[cb][key], ikv = ik2s[cb][key];
      const float emv = ems[cb][key], gmv = gm1s[cb][key];
      #pragma unroll
      for (int r = 0; r < 4; ++r) {
        float sv = sacc[nb][r];
        float num = fmaxf(fmaf(-2.0f, sv, q2r[r] + k2v), 1e-15f);
        float e = num * iq2[r] * ikv;
        float g = fmaf(e, e, e + e);
        float z = 1.0f + e + __builtin_amdgcn_sqrtf(g);
        float w = emv * __builtin_amdgcn_rcpf(z);
        pb[r][nb] = w;
        dden[r] = fmaf(w, gmv, dden[r]);
      }
    }

    // P -> LDS (wave-private rows), split-bf16
    #pragma unroll
    for (int r = 0; r < 4; ++r) {
      const int prow = 16 * wave + 4 * quad + r;
      #pragma unroll
      for (int nb = 0; nb < 2; ++nb) {
        float w = pb[r][nb];
        unsigned short hi = f2bf(w);
        unsigned short lo = f2bf(w - bf2f(hi));
        Psh[prow * 40 + 16 * nb + tx] = hi;
        Psl[prow * 40 + 16 * nb + tx] = lo;
      }
    }
    // PV: K-dim = 32 keys (single MFMA K), same-wave LDS RAW only
    bf16x8 ph = *(const bf16x8*)&Psh[(16 * wave + tx) * 40 + 8 * quad];
    bf16x8 pl = *(const bf16x8*)&Psl[(16 * wave + tx) * 40 + 8 * quad];
    #pragma unroll
    for (int nb = 0; nb < 4; ++nb) {
      const int row = 16 * nb + tx;
      const int off = row * 32 + 8 * ((quad + row) & 3);
      bf16x8 gh = *(const bf16x8*)&Gsh[cb][off];
      bf16x8 gl = *(const bf16x8*)&Gsl[cb][off];
      oacc[nb] = __builtin_amdgcn_mfma_f32_16x16x32_bf16(ph, gh, oacc[nb], 0, 0, 0);
      oacc[nb] = __builtin_amdgcn_mfma_f32_16x16x32_bf16(ph, gl, oacc[nb], 0, 0, 0);
      oacc[nb] = __builtin_amdgcn_mfma_f32_16x16x32_bf16(pl, gh, oacc[nb], 0, 0, 0);
    }
  }

  #pragma unroll
  for (int r = 0; r < 4; ++r) {
    float d = fmaxf(xor_sum16(dden[r]), 1e-10f);
    float invd = 1.0f / d;
    float tm[4]; float sq = 0.f;
    #pragma unroll
    for (int nb = 0; nb < 4; ++nb) { tm[nb] = oacc[nb][r] * invd; sq = fmaf(tm[nb], tm[nb], sq); }
    sq = xor_sum16(sq);
    const float f = 1.0f / (1.0f + sqrtf(fmaxf(1.0f - sq, 1e-15f)));
    const float n2 = sq * f * f;
    const float n = fmaxf(sqrtf(n2), 1e-15f);
    const float s2 = (n > MAXN) ? (MAXN / n) : 1.0f;
    const float fs = f * s2;
    const int qrow = r0 + 16 * wave + 4 * quad + r;
    #pragma unroll
    for (int nb = 0; nb < 4; ++nb)
      out[((size_t)(b * SS + qrow)) * DD + h * DH + 16 * nb + tx] = tm[nb] * fs;
  }
}

// ---------------- host ----------------
extern "C" void kernel_launch(void* const* d_in, const int* in_sizes, int n_in,
                              void* d_out, int out_size, void* d_ws, size_t ws_size,
                              hipStream_t stream) {
  const float* hs   = (const float*)d_in[0];
  const float* mask = (const float*)d_in[1];
  const float* qz   = (const float*)d_in[2];
  const float* qr   = (const float*)d_in[3];
  const float* kz   = (const float*)d_in[4];
  const float* kr   = (const float*)d_in[5];
  const float* vz   = (const float*)d_in[6];
  const float* vr   = (const float*)d_in[7];
  float* out = (float*)d_out;

  float* ws = (float*)d_ws;
  const size_t nQKV = (size_t)BB * NH * SS * DH;   // 2,097,152
  const size_t nStat = (size_t)BB * NH * SS;       // 32,768

  // fp32 region
  float* q2  = ws;
  float* k2  = q2 + nStat;
  float* gm1 = k2 + nStat;
  float* cx2 = gm1 + nStat;          // 2048
  float* partial = cx2 + 2048;       // 16 x 3072 col-sum partials (192 KB)

  // bf16 region (halfwords). gemm reads X/ZT while writing Q/K/GT -> all distinct.
  unsigned short* sb   = (unsigned short*)(partial + 16 * 3072);   // 16B-aligned
  unsigned short* Qhi  = sb;                  // 2M each
  unsigned short* Qlo  = Qhi + nQKV;
  unsigned short* Khi  = Qlo + nQKV;
  unsigned short* Klo  = Khi + nQKV;
  unsigned short* GThi = Klo + nQKV;
  unsigned short* GTlo = GThi + nQKV;
  unsigned short* Xhi  = GTlo + nQKV;
  unsigned short* Xlo  = Xhi + nQKV;
  unsigned short* ZThi = Xlo + nQKV;          // 3M each
  unsigned short* ZTlo = ZThi + 3 * (size_t)DD * DD;  // total ~44 MB

  prep_kernel<<<dim3(1792), 256, 0, stream>>>(
      hs, qz, kz, vz, cx2, partial, Xhi, Xlo, ZThi, ZTlo);
  gemm_mfma_kernel<<<dim3(8, 16, 3), 256, 0, stream>>>(
      Xhi, Xlo, ZThi, ZTlo, partial, qr, kr, vr, cx2,
      Qhi, Qlo, Khi, Klo, GThi, GTlo, q2, k2, gm1);
  flash_attn_kernel<<<dim3(NH, 16, BB), 256, 0, stream>>>(
      Qhi, Qlo, Khi, Klo, GThi, GTlo, q2, k2, gm1, mask, out);
}

// Round 19
// 194.510 us; speedup vs baseline: 1.4098x; 1.0113x over previous
//
#include <hip/hip_runtime.h>
#include <math.h>

// Problem constants (C = RC = 1)
#define BB 2
#define SS 1024
#define DD 1024
#define NH 16
#define DH 64
#define MAXN 0.996f   // (1 - PROJ_EPS)/RC

typedef __attribute__((ext_vector_type(8))) short bf16x8;  // MFMA A/B frag (4 VGPRs)
typedef __attribute__((ext_vector_type(4))) float f32x4;   // MFMA C/D frag

__device__ __forceinline__ float xor_sum16(float v){
  v += __shfl_xor(v, 1, 64);
  v += __shfl_xor(v, 2, 64);
  v += __shfl_xor(v, 4, 64);
  v += __shfl_xor(v, 8, 64);
  return v;
}

__device__ __forceinline__ unsigned short f2bf(float x){
  unsigned u = __builtin_bit_cast(unsigned, x);
  unsigned r = u + 0x7FFFu + ((u >> 16) & 1u);   // RNE
  return (unsigned short)(r >> 16);
}
__device__ __forceinline__ float bf2f(unsigned short b){
  unsigned u = ((unsigned)b) << 16;
  return __builtin_bit_cast(float, u);
}

// async global->LDS DMA: per-lane 16B from g, landing at wave-uniform s + lane*16
__device__ __forceinline__ void async_copy16(const unsigned short* g, unsigned short* s){
  __builtin_amdgcn_global_load_lds(
      (const __attribute__((address_space(1))) unsigned int*)g,
      (__attribute__((address_space(3))) unsigned int*)s,
      16, 0, 0);
}

// ---------------- K1: fused prep (one launch) ----------------
// v13: col_stats folded into convert_zt (partial col-sums); stats finalization
// lives in the gemm epilogue (v15, VALIDATED round 13) - no finalize kernel.
// blocks [0,1024): convert_x (split-bf16) + fused per-row ||x||^2 (2 rows/block)
// blocks [1024,1792): convert_zt (z -> split-bf16 transposed ZT[mat][n][k]) + col-partials
__global__ __launch_bounds__(256) void prep_kernel(
    const float* __restrict__ hs,
    const float* __restrict__ zq, const float* __restrict__ zk, const float* __restrict__ zv,
    float* __restrict__ cx2, float* __restrict__ partial,
    unsigned short* __restrict__ Xhi, unsigned short* __restrict__ Xlo,
    unsigned short* __restrict__ ZThi, unsigned short* __restrict__ ZTlo)
{
  __shared__ unsigned shbuf[64 * 69];     // 17.6 KB, aliased per role
  __shared__ float csred[4][64];          // cross-wave col-sum reduce (convert_zt)
  const int bid = blockIdx.x;
  const int tid = threadIdx.x;

  if (bid < 1024) {
    // ---- convert_x + row ||x||^2 (rows 2b, 2b+1) ----
    const int b = bid;
    const size_t g0 = (size_t)b * 2048 + (size_t)tid * 8;
    float acc = 0.0f;
    #pragma unroll
    for (int h = 0; h < 2; ++h) {
      float4 v = *(const float4*)(hs + g0 + 4 * h);
      float a[4] = {v.x, v.y, v.z, v.w};
      ushort4 hv, lv;
      unsigned short* hp = (unsigned short*)&hv;
      unsigned short* lp = (unsigned short*)&lv;
      #pragma unroll
      for (int j = 0; j < 4; ++j) {
        acc = fmaf(a[j], a[j], acc);
        unsigned short hi = f2bf(a[j]);
        hp[j] = hi;
        lp[j] = f2bf(a[j] - bf2f(hi));
      }
      *(ushort4*)(Xhi + g0 + 4 * h) = hv;
      *(ushort4*)(Xlo + g0 + 4 * h) = lv;
    }
    #pragma unroll
    for (int m = 1; m < 64; m <<= 1) acc += __shfl_xor(acc, m, 64);
    float* red = (float*)shbuf;
    const int wave = tid >> 6, lane = tid & 63;
    if (lane == 0) red[wave] = acc;
    __syncthreads();
    if (tid == 0)   cx2[2 * b]     = red[0] + red[1];
    if (tid == 128) cx2[2 * b + 1] = red[2] + red[3];
  } else {
    // ---- convert_zt + column-sum partials ----
    const int b2 = bid - 1024;
    const int kt = b2 & 15, nt = (b2 >> 4) & 15, mat = b2 >> 8;
    const float* z = (mat == 0) ? zq : ((mat == 1) ? zk : zv);
    const int wave = tid >> 6, lane = tid & 63;
    unsigned (*T)[69] = (unsigned(*)[69])shbuf;
    float cs[4] = {0.f, 0.f, 0.f, 0.f};
    #pragma unroll
    for (int i = 0; i < 4; ++i) {
      const int g = tid + 256 * i;
      const int kr = g >> 4, nc = (g & 15) * 4;   // nc fixed per thread
      float4 v = *(const float4*)(z + (size_t)(kt * 64 + kr) * DD + nt * 64 + nc);
      float a[4] = {v.x, v.y, v.z, v.w};
      #pragma unroll
      for (int j = 0; j < 4; ++j) {
        cs[j] = fmaf(a[j], a[j], cs[j]);
        unsigned short hi = f2bf(a[j]);
        unsigned short lo = f2bf(a[j] - bf2f(hi));
        T[kr][nc + j] = ((unsigned)lo << 16) | (unsigned)hi;
      }
    }
    // intra-wave reduce over row-groups (lanes l, l^16, l^32, l^48 share cols)
    #pragma unroll
    for (int j = 0; j < 4; ++j) {
      cs[j] += __shfl_xor(cs[j], 16, 64);
      cs[j] += __shfl_xor(cs[j], 32, 64);
    }
    if (lane < 16) {
      #pragma unroll
      for (int j = 0; j < 4; ++j) csred[wave][lane * 4 + j] = cs[j];
    }
    __syncthreads();
    #pragma unroll
    for (int i = 0; i < 4; ++i) {
      const int g = tid + 256 * i;
      const int nr = g >> 4, kc = (g & 15) * 4;
      ushort4 hv, lv;
      unsigned short* hp = (unsigned short*)&hv;
      unsigned short* lp = (unsigned short*)&lv;
      #pragma unroll
      for (int j = 0; j < 4; ++j) {
        unsigned u = T[kc + j][nr];
        hp[j] = (unsigned short)(u & 0xFFFFu);
        lp[j] = (unsigned short)(u >> 16);
      }
      const size_t ob = ((size_t)mat * DD + nt * 64 + nr) * DD + kt * 64 + kc;
      *(ushort4*)(ZThi + ob) = hv;
      *(ushort4*)(ZTlo + ob) = lv;
    }
    if (tid < 64) {
      float s = csred[0][tid] + csred[1][tid] + csred[2][tid] + csred[3][tid];
      partial[kt * 3072 + mat * DD + nt * 64 + tid] = s;   // [16][3072]
    }
  }
}

// ---------------- K2: split-bf16 MFMA GEMM + Poincare epilogue (v17) --------
// v16 (196.7us measured) + XCD supertile swizzle (T1): 1-D grid of 384 blocks,
// bid -> (mat, m-panel, n-panel) so XCD = bid%8 owns a 4x4 panel supertile:
// per-XCD per-mat working set = X 2MB + ZT 2MB = 4MB = one L2. Replaces the
// old (x=n-panel) mapping where every X m-panel was fetched by all 8 XCDs.
// Bijection: mat=bid>>7; s=bid&7; j=(bid&127)>>3; m=4*(s>>1)+(j>>2);
// n=4*(s&1)+(j&3). 128x128 tile, wave tile 64x64, BK=32, 2-buffer loop.
__global__ __launch_bounds__(256, 2) void gemm_mfma_kernel(
    const unsigned short* __restrict__ Xhi, const unsigned short* __restrict__ Xlo,
    const unsigned short* __restrict__ ZThi, const unsigned short* __restrict__ ZTlo,
    const float* __restrict__ partial,
    const float* __restrict__ rq, const float* __restrict__ rk, const float* __restrict__ rv,
    const float* __restrict__ cx2,
    unsigned short* __restrict__ Qhi, unsigned short* __restrict__ Qlo,
    unsigned short* __restrict__ Khi, unsigned short* __restrict__ Klo,
    unsigned short* __restrict__ GThi, unsigned short* __restrict__ GTlo,
    float* __restrict__ q2, float* __restrict__ k2, float* __restrict__ gm1)
{
  __shared__ __align__(16) unsigned char shmem[66560];   // 65 KB -> 2 blocks/CU
  unsigned short* Sbuf = (unsigned short*)shmem;

  // ---- supertile decode (v17) ----
  const int bid = blockIdx.x;
  const int mat = bid >> 7;                  // 0..2
  const int sxcd = bid & 7;                  // XCD id (bid % 8)
  const int jloc = (bid & 127) >> 3;         // 0..15 within supertile
  const int mpan = 4 * (sxcd >> 1) + (jloc >> 2);   // m-panel 0..15
  const int npan = 4 * (sxcd & 1) + (jloc & 3);     // n-panel 0..7

  float* Stat = (mat == 0) ? q2 : ((mat == 1) ? k2 : gm1);
  unsigned short* Bh = (mat == 0) ? Qhi : Khi;
  unsigned short* Bl = (mat == 0) ? Qlo : Klo;

  const int n0 = npan * 128;
  const int m0 = mpan * 128;
  const int tid = threadIdx.x;
  const int wave = tid >> 6, lane = tid & 63;
  const int tx = lane & 15, quad = lane >> 4;
  const int wrow = wave >> 1;                // rows [64*wrow, +64)
  const int wcol = wave & 1;                 // cols [64*wcol, +64) = head wcol

  const int l4r = lane >> 2;
  const int l4c = 8 * (((lane & 3) - (l4r >> 1)) & 3);
  const unsigned short* abase =
      (wave == 0) ? Xhi : (wave == 1) ? Xlo : (wave == 2) ? ZThi : ZTlo;
  const size_t rowbase = (wave < 2) ? (size_t)m0 : (size_t)(mat * DD + n0);
  const unsigned short* P[8];
  #pragma unroll
  for (int i = 0; i < 8; ++i)
    P[i] = abase + (rowbase + i * 16 + l4r) * DD + l4c;
  const int ldsw = 4096 * wave;              // wave's 8KB region within a buffer

  const int koff = 8 * ((quad + (tx >> 1)) & 3);

  const f32x4 z4 = {0.f, 0.f, 0.f, 0.f};
  f32x4 acc[4][4];
  #pragma unroll
  for (int mb = 0; mb < 4; ++mb)
    #pragma unroll
    for (int nb = 0; nb < 4; ++nb) acc[mb][nb] = z4;

  #pragma unroll
  for (int i = 0; i < 8; ++i) {
    async_copy16(P[i], Sbuf + ldsw + 512 * i);
    P[i] += 32;
  }

  for (int kt = 0; kt < 32; ++kt) {
    __syncthreads();                         // tile kt landed; buf[kt+1 &1] free
    if (kt < 31) {
      unsigned short* Bn = Sbuf + 16384 * ((kt + 1) & 1);
      #pragma unroll
      for (int i = 0; i < 8; ++i) {
        async_copy16(P[i], Bn + ldsw + 512 * i);
        P[i] += 32;
      }
    }
    const unsigned short* Bc = Sbuf + 16384 * (kt & 1);

    bf16x8 a_h[4], a_l[4];
    #pragma unroll
    for (int mb = 0; mb < 4; ++mb) {
      const int ar = 64 * wrow + 16 * mb + tx;
      a_h[mb] = *(const bf16x8*)&Bc[ar * 32 + koff];
      a_l[mb] = *(const bf16x8*)&Bc[4096 + ar * 32 + koff];
    }
    #pragma unroll
    for (int nb = 0; nb < 4; ++nb) {
      const int br = 64 * wcol + 16 * nb + tx;
      bf16x8 b_h = *(const bf16x8*)&Bc[8192 + br * 32 + koff];
      bf16x8 b_l = *(const bf16x8*)&Bc[12288 + br * 32 + koff];
      #pragma unroll
      for (int mb = 0; mb < 4; ++mb)
        acc[mb][nb] = __builtin_amdgcn_mfma_f32_16x16x32_bf16(a_h[mb], b_h, acc[mb][nb], 0, 0, 0);
      #pragma unroll
      for (int mb = 0; mb < 4; ++mb)
        acc[mb][nb] = __builtin_amdgcn_mfma_f32_16x16x32_bf16(a_h[mb], b_l, acc[mb][nb], 0, 0, 0);
      #pragma unroll
      for (int mb = 0; mb < 4; ++mb)
        acc[mb][nb] = __builtin_amdgcn_mfma_f32_16x16x32_bf16(a_l[mb], b_h, acc[mb][nb], 0, 0, 0);
    }
  }

  // ---- inlined column stats (validated round 13) ----
  float acolv[4], bcolv[4], scolv[4];
  {
    const float* rarr = (mat == 0) ? rq : ((mat == 1) ? rk : rv);
    #pragma unroll
    for (int nb = 0; nb < 4; ++nb) {
      const int c = n0 + 64 * wcol + 16 * nb + tx;
      const int colg = mat * DD + c;
      float s = 0.f;
      #pragma unroll
      for (int rc = 0; rc < 16; ++rc) s += partial[rc * 3072 + colg];
      const float n = fmaxf(sqrtf(s), 1e-15f);
      const float rr2 = 2.0f * rarr[c];
      acolv[nb] = 2.0f * coshf(rr2) / n;
      bcolv[nb] = sinhf(rr2);
      scolv[nb] = 2.0f * n;
    }
  }

  const int head = npan * 2 + wcol;
  unsigned* Tr = (unsigned*)shmem;           // 2*128*65 unsigned (mat==2 only)
  if (mat == 2) __syncthreads();             // all waves done with Sbuf before reuse

  #pragma unroll
  for (int mb = 0; mb < 4; ++mb) {
    #pragma unroll
    for (int r = 0; r < 4; ++r) {
      const int sl = 64 * wrow + 16 * mb + 4 * quad + r;
      const int row = m0 + sl;
      const float c2 = cx2[row];
      const float inv = 1.0f / fmaxf(1.0f - c2, 1e-15f);
      const float onec = 1.0f + c2;
      float yv[4];
      #pragma unroll
      for (int nb = 0; nb < 4; ++nb) {
        const float accv = acc[mb][nb][r];
        const float u = fmaf(accv, acolv[nb], -(onec * bcolv[nb])) * inv;
        const float a = fabsf(u);
        const float t = a + sqrtf(fmaf(a, a, 1.0f));
        const float p = __builtin_amdgcn_exp2f(scolv[nb] * __builtin_amdgcn_logf(t));
        float y = 0.5f * (p - __builtin_amdgcn_rcpf(p));
        yv[nb] = copysignf(y, u);
      }
      const int b = row >> 10, s = row & 1023;
      float n2 = 0.f;
      #pragma unroll
      for (int j = 0; j < 4; ++j) n2 = fmaf(yv[j], yv[j], n2);
      n2 = xor_sum16(n2);
      float n = fmaxf(sqrtf(n2), 1e-15f);
      float s1 = (n > MAXN) ? (MAXN / n) : 1.0f;      // project #1
      n2 = n2 * s1 * s1;
      float f = 1.0f / (1.0f + sqrtf(1.0f + n2));     // exp-map scaling
      float fs = s1 * f;
      n2 = n2 * f * f;
      float nb2 = fmaxf(sqrtf(n2), 1e-15f);
      float s2f = (nb2 > MAXN) ? (MAXN / nb2) : 1.0f; // project #2
      fs *= s2f;
      n2 = n2 * s2f * s2f;

      const size_t bh = (size_t)(b * NH + head);
      const size_t outbase = (bh * SS + s) * DH;
      if (mat == 2) {
        const float gamma = 2.0f / fmaxf(1.0f - n2, 1e-15f);
        #pragma unroll
        for (int j = 0; j < 4; ++j) {
          const float v = yv[j] * fs * gamma;
          const unsigned short hi = f2bf(v);
          const unsigned short lo = f2bf(v - bf2f(hi));
          Tr[(wcol * 128 + sl) * 65 + 16 * j + tx] = ((unsigned)lo << 16) | (unsigned)hi;
        }
        if (tx == 0) Stat[bh * SS + s] = gamma - 1.0f;
      } else {
        #pragma unroll
        for (int j = 0; j < 4; ++j) {
          const float v = yv[j] * fs;
          const unsigned short hi = f2bf(v);
          const unsigned short lo = f2bf(v - bf2f(hi));
          Bh[outbase + 16 * j + tx] = hi;
          Bl[outbase + 16 * j + tx] = lo;
        }
        if (tx == 0) Stat[bh * SS + s] = n2;
      }
    }
  }

  if (mat == 2) {                            // cooperative transposed writeout
    __syncthreads();
    const int bb = m0 >> 10, sbase = m0 & 1023;
    #pragma unroll
    for (int i = 0; i < 4; ++i) {
      const int task = tid + 256 * i;        // 1024 tasks: 128 (h,dh) rows x 8 s-chunks
      const int rowid = task >> 3;
      const int hh = rowid >> 6, dh = rowid & 63;
      const int sc = (task & 7) * 16;
      unsigned short hbuf[16] __attribute__((aligned(16)));
      unsigned short lbuf[16] __attribute__((aligned(16)));
      #pragma unroll
      for (int s = 0; s < 16; ++s) {
        unsigned u = Tr[(hh * 128 + sc + s) * 65 + dh];
        hbuf[s] = (unsigned short)(u & 0xFFFFu);
        lbuf[s] = (unsigned short)(u >> 16);
      }
      const int hg = npan * 2 + hh;
      const size_t ob = (((size_t)(bb * NH + hg)) * DH + dh) * SS + sbase + sc;
      *(uint4*)(GThi + ob)     = *(uint4*)&hbuf[0];
      *(uint4*)(GThi + ob + 8) = *(uint4*)&hbuf[8];
      *(uint4*)(GTlo + ob)     = *(uint4*)&lbuf[0];
      *(uint4*)(GTlo + ob + 8) = *(uint4*)&lbuf[8];
    }
  }
}

// ---------------- K3: MFMA flash-style hyperbolic attention (v14) ----------
// DMA-staged, 2-buffer, ONE barrier/iter (validated round 8/13/17). KVBLK=32.
__global__ __launch_bounds__(256) void flash_attn_kernel(
    const unsigned short* __restrict__ Qhi, const unsigned short* __restrict__ Qlo,
    const unsigned short* __restrict__ Khi, const unsigned short* __restrict__ Klo,
    const unsigned short* __restrict__ GThi, const unsigned short* __restrict__ GTlo,
    const float* __restrict__ q2a, const float* __restrict__ k2a, const float* __restrict__ gm1a,
    const float* __restrict__ mask, float* __restrict__ out)
{
  __shared__ unsigned short Ksh[2][2048];    // [buf][32 key-rows x 64 dh] swizzled
  __shared__ unsigned short Ksl[2][2048];
  __shared__ unsigned short Gsh[2][2048];    // [buf][64 dh-rows x 32 keys] swizzled
  __shared__ unsigned short Gsl[2][2048];
  __shared__ unsigned short Psh[64 * 40];    // P rows (wave-private 16-row bands)
  __shared__ unsigned short Psl[64 * 40];
  __shared__ float k2s[2][32], ik2s[2][32], gm1s[2][32], ems[2][32];

  const int h = blockIdx.x, qt = blockIdx.y, b = blockIdx.z;   // XCD = h%8
  const int bh = b * NH + h;
  const int tid = threadIdx.x;
  const int wave = tid >> 6, lane = tid & 63;
  const int tx = lane & 15, quad = lane >> 4;
  const int r0 = qt * 64;

  bf16x8 qa_h[2], qa_l[2];
  {
    const size_t qoff = ((size_t)bh * SS + r0 + 16 * wave + tx) * DH;
    #pragma unroll
    for (int kc = 0; kc < 2; ++kc) {
      qa_h[kc] = *(const bf16x8*)(Qhi + qoff + 32 * kc + 8 * quad);
      qa_l[kc] = *(const bf16x8*)(Qlo + qoff + 32 * kc + 8 * quad);
    }
  }
  float q2r[4], iq2[4];
  #pragma unroll
  for (int r = 0; r < 4; ++r) {
    q2r[r] = q2a[(size_t)bh * SS + r0 + 16 * wave + 4 * quad + r];
    iq2[r] = 2.0f / fmaxf(1.0f - q2r[r], 1e-15f);
  }

  const f32x4 zero4 = {0.f, 0.f, 0.f, 0.f};
  f32x4 oacc[4] = {zero4, zero4, zero4, zero4};
  float dden[4] = {0.f, 0.f, 0.f, 0.f};

  const size_t kbase = (size_t)bh * SS * DH;   // K arrays: [key][dh]
  const size_t gbase = (size_t)bh * DH * SS;   // GT arrays: [dh][key]

  const unsigned short* sArr =
      (wave == 0) ? Khi : (wave == 1) ? Klo : (wave == 2) ? GThi : GTlo;
  const unsigned short* sBase = sArr + ((wave < 2) ? kbase : gbase);
  const int tAdv = (wave < 2) ? 32 * DH : 32;   // per-tile source advance (elems)
  int srcoff[4];
  if (wave < 2) {
    #pragma unroll
    for (int i = 0; i < 4; ++i) {
      const int r = 8 * i + (lane >> 3);
      srcoff[i] = r * DH + 8 * (((lane & 7) - r) & 7);
    }
  } else {
    #pragma unroll
    for (int i = 0; i < 4; ++i) {
      const int r = 16 * i + (lane >> 2);
      srcoff[i] = r * SS + 8 * (((lane & 3) - r) & 3);
    }
  }
  unsigned short* ldsDst[2];
  ldsDst[0] = (wave == 0) ? Ksh[0] : (wave == 1) ? Ksl[0] : (wave == 2) ? Gsh[0] : Gsl[0];
  ldsDst[1] = (wave == 0) ? Ksh[1] : (wave == 1) ? Ksl[1] : (wave == 2) ? Gsh[1] : Gsl[1];

  float s_k2 = 0.f, s_gm1 = 0.f, s_ms = 0.f;

  {
    const unsigned short* s = sBase;
    #pragma unroll
    for (int i = 0; i < 4; ++i) async_copy16(s + srcoff[i], ldsDst[0] + i * 512);
  }
  if (tid < 32) {
    s_k2  = k2a[(size_t)bh * SS + tid];
    s_gm1 = gm1a[(size_t)bh * SS + tid];
    s_ms  = mask[(size_t)b * SS + tid];
    k2s[0][tid]  = s_k2;
    ik2s[0][tid] = 1.0f / fmaxf(1.0f - s_k2, 1e-15f);
    gm1s[0][tid] = s_gm1;
    ems[0][tid]  = __expf(s_ms);
    s_k2  = k2a[(size_t)bh * SS + 32 + tid];
    s_gm1 = gm1a[(size_t)bh * SS + 32 + tid];
    s_ms  = mask[(size_t)b * SS + 32 + tid];
  }

  for (int kt = 0; kt < 32; ++kt) {
    __syncthreads();                         // tile kt + stats[kt&1] ready
    if (kt < 31) {
      const int nbuf = (kt + 1) & 1;
      const unsigned short* s = sBase + (size_t)(kt + 1) * tAdv;
      #pragma unroll
      for (int i = 0; i < 4; ++i) async_copy16(s + srcoff[i], ldsDst[nbuf] + i * 512);
      if (tid < 32) {
        k2s[nbuf][tid]  = s_k2;
        ik2s[nbuf][tid] = 1.0f / fmaxf(1.0f - s_k2, 1e-15f);
        gm1s[nbuf][tid] = s_gm1;
        ems[nbuf][tid]  = __expf(s_ms);
        if (kt < 30) {
          const int t2 = (kt + 2) * 32;
          s_k2  = k2a[(size_t)bh * SS + t2 + tid];
          s_gm1 = gm1a[(size_t)bh * SS + t2 + tid];
          s_ms  = mask[(size_t)b * SS + t2 + tid];
        }
      }
    }
    const int cb = kt & 1;

    // QK^T: S[64 q][32 key], K-dim = dh (2 kc steps)
    f32x4 sacc[2] = {zero4, zero4};
    #pragma unroll
    for (int kc = 0; kc < 2; ++kc) {
      #pragma unroll
      for (int nb = 0; nb < 2; ++nb) {
        const int row = 16 * nb + tx;
        const int off = row * 64 + 8 * (((4 * kc + quad) + row) & 7);
        bf16x8 kh = *(const bf16x8*)&Ksh[cb][off];
        bf16x8 kl = *(const bf16x8*)&Ksl[cb][off];
        sacc[nb] = __builtin_amdgcn_mfma_f32_16x16x32_bf16(qa_h[kc], kh, sacc[nb], 0, 0, 0);
        sacc[nb] = __builtin_amdgcn_mfma_f32_16x16x32_bf16(qa_h[kc], kl, sacc[nb], 0, 0, 0);
        sacc[nb] = __builtin_amdgcn_mfma_f32_16x16x32_bf16(qa_l[kc], kh, sacc[nb], 0, 0, 0);
      }
    }

    // hyperbolic weights
    float pb[4][2];
    #pragma unroll
    for (int nb = 0; nb < 2; ++nb) {
      const int key = 16 * nb + tx;
      const float k2v = k2s[cb][key], ikv = ik2s[cb][key];
      const float emv = ems[cb][key], gmv = gm1s[cb][key];
      #pragma unroll
      for (int r = 0; r < 4; ++r) {
        float sv = sacc[nb][r];
        float num = fmaxf(fmaf(-2.0f, sv, q2r[r] + k2v), 1e-15f);
        float e = num * iq2[r] * ikv;
        float g = fmaf(e, e, e + e);
        float z = 1.0f + e + __builtin_amdgcn_sqrtf(g);
        float w = emv * __builtin_amdgcn_rcpf(z);
        pb[r][nb] = w;
        dden[r] = fmaf(w, gmv, dden[r]);
      }
    }

    // P -> LDS (wave-private rows), split-bf16
    #pragma unroll
    for (int r = 0; r < 4; ++r) {
      const int prow = 16 * wave + 4 * quad + r;
      #pragma unroll
      for (int nb = 0; nb < 2; ++nb) {
        float w = pb[r][nb];
        unsigned short hi = f2bf(w);
        unsigned short lo = f2bf(w - bf2f(hi));
        Psh[prow * 40 + 16 * nb + tx] = hi;
        Psl[prow * 40 + 16 * nb + tx] = lo;
      }
    }
    // PV: K-dim = 32 keys (single MFMA K), same-wave LDS RAW only
    bf16x8 ph = *(const bf16x8*)&Psh[(16 * wave + tx) * 40 + 8 * quad];
    bf16x8 pl = *(const bf16x8*)&Psl[(16 * wave + tx) * 40 + 8 * quad];
    #pragma unroll
    for (int nb = 0; nb < 4; ++nb) {
      const int row = 16 * nb + tx;
      const int off = row * 32 + 8 * ((quad + row) & 3);
      bf16x8 gh = *(const bf16x8*)&Gsh[cb][off];
      bf16x8 gl = *(const bf16x8*)&Gsl[cb][off];
      oacc[nb] = __builtin_amdgcn_mfma_f32_16x16x32_bf16(ph, gh, oacc[nb], 0, 0, 0);
      oacc[nb] = __builtin_amdgcn_mfma_f32_16x16x32_bf16(ph, gl, oacc[nb], 0, 0, 0);
      oacc[nb] = __builtin_amdgcn_mfma_f32_16x16x32_bf16(pl, gh, oacc[nb], 0, 0, 0);
    }
  }

  #pragma unroll
  for (int r = 0; r < 4; ++r) {
    float d = fmaxf(xor_sum16(dden[r]), 1e-10f);
    float invd = 1.0f / d;
    float tm[4]; float sq = 0.f;
    #pragma unroll
    for (int nb = 0; nb < 4; ++nb) { tm[nb] = oacc[nb][r] * invd; sq = fmaf(tm[nb], tm[nb], sq); }
    sq = xor_sum16(sq);
    const float f = 1.0f / (1.0f + sqrtf(fmaxf(1.0f - sq, 1e-15f)));
    const float n2 = sq * f * f;
    const float n = fmaxf(sqrtf(n2), 1e-15f);
    const float s2 = (n > MAXN) ? (MAXN / n) : 1.0f;
    const float fs = f * s2;
    const int qrow = r0 + 16 * wave + 4 * quad + r;
    #pragma unroll
    for (int nb = 0; nb < 4; ++nb)
      out[((size_t)(b * SS + qrow)) * DD + h * DH + 16 * nb + tx] = tm[nb] * fs;
  }
}

// ---------------- host ----------------
extern "C" void kernel_launch(void* const* d_in, const int* in_sizes, int n_in,
                              void* d_out, int out_size, void* d_ws, size_t ws_size,
                              hipStream_t stream) {
  const float* hs   = (const float*)d_in[0];
  const float* mask = (const float*)d_in[1];
  const float* qz   = (const float*)d_in[2];
  const float* qr   = (const float*)d_in[3];
  const float* kz   = (const float*)d_in[4];
  const float* kr   = (const float*)d_in[5];
  const float* vz   = (const float*)d_in[6];
  const float* vr   = (const float*)d_in[7];
  float* out = (float*)d_out;

  float* ws = (float*)d_ws;
  const size_t nQKV = (size_t)BB * NH * SS * DH;   // 2,097,152
  const size_t nStat = (size_t)BB * NH * SS;       // 32,768

  // fp32 region
  float* q2  = ws;
  float* k2  = q2 + nStat;
  float* gm1 = k2 + nStat;
  float* cx2 = gm1 + nStat;          // 2048
  float* partial = cx2 + 2048;       // 16 x 3072 col-sum partials (192 KB)

  // bf16 region (halfwords). gemm reads X/ZT while writing Q/K/GT -> all distinct.
  unsigned short* sb   = (unsigned short*)(partial + 16 * 3072);   // 16B-aligned
  unsigned short* Qhi  = sb;                  // 2M each
  unsigned short* Qlo  = Qhi + nQKV;
  unsigned short* Khi  = Qlo + nQKV;
  unsigned short* Klo  = Khi + nQKV;
  unsigned short* GThi = Klo + nQKV;
  unsigned short* GTlo = GThi + nQKV;
  unsigned short* Xhi  = GTlo + nQKV;
  unsigned short* Xlo  = Xhi + nQKV;
  unsigned short* ZThi = Xlo + nQKV;          // 3M each
  unsigned short* ZTlo = ZThi + 3 * (size_t)DD * DD;  // total ~44 MB

  prep_kernel<<<dim3(1792), 256, 0, stream>>>(
      hs, qz, kz, vz, cx2, partial, Xhi, Xlo, ZThi, ZTlo);
  gemm_mfma_kernel<<<dim3(384), 256, 0, stream>>>(
      Xhi, Xlo, ZThi, ZTlo, partial, qr, kr, vr, cx2,
      Qhi, Qlo, Khi, Klo, GThi, GTlo, q2, k2, gm1);
  flash_attn_kernel<<<dim3(NH, 16, BB), 256, 0, stream>>>(
      Qhi, Qlo, Khi, Klo, GThi, GTlo, q2, k2, gm1, mask, out);
}